// Round 5
// baseline (254.627 us; speedup 1.0000x reference)
//
#include <hip/hip_runtime.h>
#include <hip/hip_fp16.h>
#include <cmath>

// Fixed problem shape: x = (8, 3, 1024, 1024) fp32.
#define HH   1024
#define WW   1024
#define HW   (HH * WW)

#define SW    64      // tile width  (output cols per block)
#define TH    64      // tile height (output rows per block)
#define T31R  94      // TH + 30
#define T7R   70      // TH + 6
#define NIT   6       // phase-1 iterations (6*16 = 96 >= 94 staged rows)
#define SPX   96      // stage row width in px (64 + 16 left + 16 right halo)
#define SOFF  16      // stage col s  <->  image col x0 - SOFF + s
#define UPR   24      // float4 units per stage row (24*4 = 96)

// ---- compile-time gaussian weights (matches np: exp(-d^2/(2 sigma^2)) / sum) ----
constexpr double cexp(double v) {
    double term = 1.0, sum = 1.0;
    for (int i = 1; i < 64; ++i) { term *= v / (double)i; sum += term; }
    return sum;
}
struct GW { float g31[31]; float g7[7]; };
constexpr GW make_gw() {
    GW r{};
    double t31[31]; double s31 = 0.0;
    for (int i = 0; i < 31; ++i) { double d = (double)(i - 15); t31[i] = cexp(-d * d / 128.0); s31 += t31[i]; }
    for (int i = 0; i < 31; ++i) r.g31[i] = (float)(t31[i] / s31);
    double t7[7]; double s7 = 0.0;
    for (int i = 0; i < 7; ++i) { double d = (double)(i - 3); t7[i] = cexp(-d * d / 4.5); s7 += t7[i]; }
    for (int i = 0; i < 7; ++i) r.g7[i] = (float)(t7[i] / s7);
    return r;
}
__constant__ GW GWC = make_gw();

// ---------------------------------------------------------------------------
// V5 vs V4 (dispatch 78µs flat across 3 different schedules; VALU 32%,
// HBM 34%, occupancy 32%, nothing saturated): the invariant was 16 waves/CU
// (LDS-capped 4 blocks/CU). ILP scheduling is exhausted -> buy TLP instead.
// Tile height 128 -> 64:
//   LDS = 94*64*2 + 70*64*2 + 3072 = 24064 B -> 6 blocks/CU = 24 waves/CU
//   (+50% latency hiding), launch_bounds(256,6).
//   Grid 2048 = 8 img x 16 strips x 16 bands; 1.33 rounds refill the CUs
//   as blocks retire. Halo tax: staged rows/output row 1.47 vs 1.23
//   (+~12 MB fetch, ~+2us HBM) — traded for removing ~20us of stall.
// Carried from V4: branch-free masked staging, sched_barrier(0) pinning of
// prefetch, barrier-free phase 1 (per-wave private stage rows), single
// __syncthreads, phase-2 4 cols/thread direct ds_read_b64 taps, rcp.
// ---------------------------------------------------------------------------
__global__ __launch_bounds__(256, 6)
void fused_tile(const float* __restrict__ x,
                const float* __restrict__ clar,
                const float* __restrict__ tex,
                float* __restrict__ out) {
    __shared__ __align__(16) __half t31s [T31R][SW];
    __shared__ __align__(16) __half t7s  [T7R][SW];
    __shared__ __align__(16) __half stage[4][4][SPX];   // per-wave private

    // XCD swizzle: the two vertically-adjacent bands of one (img,strip)
    // column land on the same XCD so the 30-row halo overlap reuses L2.
    const int id    = blockIdx.x;
    const int xcd   = id & 7;
    const int j8    = id >> 3;             // 0..255
    const int combo = j8 & 127;            // img*16 + strip
    const int sub   = j8 >> 7;             // 0..1
    const int band  = xcd * 2 + sub;       // 0..15
    const int img   = combo >> 4;
    const int strip = combo & 15;

    const int y0 = band * TH;
    const int x0 = strip * SW;
    const int t  = threadIdx.x;
    const int w    = t >> 6;               // wave 0..3
    const int lane = t & 63;

    const float* xb = x   + (size_t)img * 3 * HW;
    float*       ob = out + (size_t)img * 3 * HW;

    // ---- per-wave staging geometry: 4 rows x 24 units = 96 units over 64
    // lanes. unit0 = lane; unit1 = lane+64 (lanes >= 32 produce benign
    // duplicate writes of valid slots -> fully branch-free). ----
    const int r0s = lane / UPR;                 // 0..2
    const int c0s = lane - UPR * r0s;
    const int u1  = lane + 64;                  // 64..127
    const int r1r = u1 / UPR;                   // 2..5
    const int r1s = r1r > 3 ? 3 : r1r;          // clamp -> duplicate slots
    const int c1s = u1 - UPR * r1r;             // 0..23
    const int col0 = x0 - SOFF + 4 * c0s;
    const int col1 = x0 - SOFF + 4 * c1s;
    const int col0c = col0 < 0 ? 0 : (col0 > WW - 4 ? WW - 4 : col0);
    const int col1c = col1 < 0 ? 0 : (col1 > WW - 4 ? WW - 4 : col1);
    const float cm0 = ((unsigned)col0 < (unsigned)WW) ? 1.f : 0.f;
    const float cm1 = ((unsigned)col1 < (unsigned)WW) ? 1.f : 0.f;

    float4 R0, G0, B0, R1, G1, B1;
    float  mk0, mk1;

    // issue iteration `it`'s global loads into registers — UNCONDITIONAL
    // (clamped addresses), masks applied at consume time.
    auto issue = [&](int it) {
        const int gbase = it * 16;
        {
            const int tr = gbase + 4 * w + r0s;
            const int y  = y0 - 15 + tr;
            const int yc = y < 0 ? 0 : (y > HH - 1 ? HH - 1 : y);
            mk0 = (tr < T31R && (unsigned)y < (unsigned)HH) ? cm0 : 0.f;
            const float* xr = xb + (size_t)yc * WW + col0c;
            R0 = *(const float4*)(xr);
            G0 = *(const float4*)(xr + HW);
            B0 = *(const float4*)(xr + 2 * HW);
        }
        {
            const int tr = gbase + 4 * w + r1s;
            const int y  = y0 - 15 + tr;
            const int yc = y < 0 ? 0 : (y > HH - 1 ? HH - 1 : y);
            mk1 = (tr < T31R && (unsigned)y < (unsigned)HH) ? cm1 : 0.f;
            const float* xr = xb + (size_t)yc * WW + col1c;
            R1 = *(const float4*)(xr);
            G1 = *(const float4*)(xr + HW);
            B1 = *(const float4*)(xr + 2 * HW);
        }
    };

    issue(0);   // prologue
    __builtin_amdgcn_sched_barrier(0);

    // -------- phase 1: barrier-free; wave w stages and h-blurs its own
    // rows tr = 16*it + 4w + r. --------
    for (int it = 0; it < NIT; ++it) {
        // consume prefetched regs -> masked fp16 luma into stage
        {
            union { float2 f; __half2 h[2]; } W;
            W.h[0] = __floats2half2_rn(mk0 * fmaf(0.2126f, R0.x, fmaf(0.7152f, G0.x, 0.0722f * B0.x)),
                                       mk0 * fmaf(0.2126f, R0.y, fmaf(0.7152f, G0.y, 0.0722f * B0.y)));
            W.h[1] = __floats2half2_rn(mk0 * fmaf(0.2126f, R0.z, fmaf(0.7152f, G0.z, 0.0722f * B0.z)),
                                       mk0 * fmaf(0.2126f, R0.w, fmaf(0.7152f, G0.w, 0.0722f * B0.w)));
            *(float2*)&stage[w][r0s][4 * c0s] = W.f;   // 8-byte aligned
            union { float2 f; __half2 h[2]; } V;
            V.h[0] = __floats2half2_rn(mk1 * fmaf(0.2126f, R1.x, fmaf(0.7152f, G1.x, 0.0722f * B1.x)),
                                       mk1 * fmaf(0.2126f, R1.y, fmaf(0.7152f, G1.y, 0.0722f * B1.y)));
            V.h[1] = __floats2half2_rn(mk1 * fmaf(0.2126f, R1.z, fmaf(0.7152f, G1.z, 0.0722f * B1.z)),
                                       mk1 * fmaf(0.2126f, R1.w, fmaf(0.7152f, G1.w, 0.0722f * B1.w)));
            *(float2*)&stage[w][r1s][4 * c1s] = V.f;
        }

        // issue next iteration's loads and FENCE: the scheduler cannot sink
        // them past this point, so the h-blur below covers their latency.
        if (it + 1 < NIT) {
            issue(it + 1);
        }
        __builtin_amdgcn_sched_barrier(0);

        // h-blur: thread -> stage row (t>>4)&3 of its own wave, 4 px at 4*(t&15)
        {
            const int lr = (t >> 4) & 3;
            const int c  = t & 15;
            const int tr = it * 16 + (t >> 4);
            if (tr < T31R) {
                float win[36];
                #pragma unroll
                for (int q = 0; q < 9; ++q) {
                    union { float2 f; __half2 h[2]; } U;
                    // win[i] <-> stage col 4c+i <-> image col x0-16+4c+i
                    U.f = *(const float2*)&stage[w][lr][4 * c + 4 * q];  // 8B aligned
                    const float2 a = __half22float2(U.h[0]);
                    const float2 b = __half22float2(U.h[1]);
                    win[4 * q]     = a.x; win[4 * q + 1] = a.y;
                    win[4 * q + 2] = b.x; win[4 * q + 3] = b.y;
                }
                float o[4] = {0.f, 0.f, 0.f, 0.f};
                float p[4] = {0.f, 0.f, 0.f, 0.f};
                #pragma unroll
                for (int s = 0; s < 31; ++s) {
                    const float g = GWC.g31[s];
                    o[0] = fmaf(g, win[1 + s], o[0]);
                    o[1] = fmaf(g, win[2 + s], o[1]);
                    o[2] = fmaf(g, win[3 + s], o[2]);
                    o[3] = fmaf(g, win[4 + s], o[3]);
                }
                #pragma unroll
                for (int s = 0; s < 7; ++s) {
                    const float g = GWC.g7[s];
                    p[0] = fmaf(g, win[13 + s], p[0]);
                    p[1] = fmaf(g, win[14 + s], p[1]);
                    p[2] = fmaf(g, win[15 + s], p[2]);
                    p[3] = fmaf(g, win[16 + s], p[3]);
                }
                union { float2 f; __half2 h[2]; } W;
                W.h[0] = __floats2half2_rn(o[0], o[1]);
                W.h[1] = __floats2half2_rn(o[2], o[3]);
                *(float2*)&t31s[tr][4 * c] = W.f;
                if (tr >= 12 && tr < 12 + T7R) {
                    union { float2 f; __half2 h[2]; } V;
                    V.h[0] = __floats2half2_rn(p[0], p[1]);
                    V.h[1] = __floats2half2_rn(p[2], p[3]);
                    *(float2*)&t7s[tr - 12][4 * c] = V.f;
                }
            }
        }
        // NO __syncthreads here
    }

    __syncthreads();   // the ONLY barrier: t31s/t7s complete before phase 2

    // -------- phase 2: vertical blurs + combine, 4 cols/thread, direct
    // b64 tap reads from LDS (no register ring). --------
    const float ca = tanhf(clar[0]) * 0.5f;
    const float ta = tanhf(tex[0]) * 0.3f;

    const int rg = t >> 4;            // row group 0..15
    const int r0 = rg * 4;            // output rows r0..r0+3 (tile-rel)
    const int cc = 4 * (t & 15);      // col within tile, float4-aligned

    // prefetch x row j=0 (L2/L3-hot re-read)
    const float* p0 = xb + (size_t)(y0 + r0) * WW + x0 + cc;
    float4 R  = *(const float4*)(p0);
    float4 G  = *(const float4*)(p0 + HW);
    float4 Bc = *(const float4*)(p0 + 2 * HW);
    __builtin_amdgcn_sched_barrier(0);

    #pragma unroll
    for (int j = 0; j < 4; ++j) {
        // issue next row's x loads before the conv chain (latency cover)
        float4 Rn, Gn, Bn;
        if (j < 3) {
            const float* pn = xb + (size_t)(y0 + r0 + j + 1) * WW + x0 + cc;
            Rn = *(const float4*)(pn);
            Gn = *(const float4*)(pn + HW);
            Bn = *(const float4*)(pn + 2 * HW);
        }
        __builtin_amdgcn_sched_barrier(0);

        float4 a31 = make_float4(0.f, 0.f, 0.f, 0.f);
        #pragma unroll
        for (int q = 0; q < 31; ++q) {
            union { float2 f; __half2 h[2]; } U;
            U.f = *(const float2*)&t31s[r0 + j + q][cc];   // ds_read_b64
            const float2 a = __half22float2(U.h[0]);
            const float2 b = __half22float2(U.h[1]);
            const float g = GWC.g31[q];
            a31.x = fmaf(g, a.x, a31.x);
            a31.y = fmaf(g, a.y, a31.y);
            a31.z = fmaf(g, b.x, a31.z);
            a31.w = fmaf(g, b.y, a31.w);
        }
        float4 a7 = make_float4(0.f, 0.f, 0.f, 0.f);
        #pragma unroll
        for (int q = 0; q < 7; ++q) {
            union { float2 f; __half2 h[2]; } U;
            U.f = *(const float2*)&t7s[r0 + j + q][cc];    // ds_read_b64
            const float2 a = __half22float2(U.h[0]);
            const float2 b = __half22float2(U.h[1]);
            const float g = GWC.g7[q];
            a7.x = fmaf(g, a.x, a7.x);
            a7.y = fmaf(g, a.y, a7.y);
            a7.z = fmaf(g, b.x, a7.z);
            a7.w = fmaf(g, b.y, a7.w);
        }

        const int y = y0 + r0 + j;
        float* qo = ob + (size_t)y * WW + x0 + cc;

        float4 o0, o1, o2;
        {
            const float L0 = fmaf(0.2126f, R.x, fmaf(0.7152f, G.x, 0.0722f * Bc.x));
            const float L1 = fmaf(0.2126f, R.y, fmaf(0.7152f, G.y, 0.0722f * Bc.y));
            const float L2 = fmaf(0.2126f, R.z, fmaf(0.7152f, G.z, 0.0722f * Bc.z));
            const float L3 = fmaf(0.2126f, R.w, fmaf(0.7152f, G.w, 0.0722f * Bc.w));
            const float e0 = L0 + ca * (L0 - a31.x) + ta * (L0 - a7.x);
            const float e1 = L1 + ca * (L1 - a31.y) + ta * (L1 - a7.y);
            const float e2 = L2 + ca * (L2 - a31.z) + ta * (L2 - a7.z);
            const float e3 = L3 + ca * (L3 - a31.w) + ta * (L3 - a7.w);
            // v_rcp_f32 approx: rel err ~1ulp, far below the 3.9e-3 tolerance
            const float r0r = (e0 + 1e-6f) * __builtin_amdgcn_rcpf(L0 + 1e-6f);
            const float r1r = (e1 + 1e-6f) * __builtin_amdgcn_rcpf(L1 + 1e-6f);
            const float r2r = (e2 + 1e-6f) * __builtin_amdgcn_rcpf(L2 + 1e-6f);
            const float r3r = (e3 + 1e-6f) * __builtin_amdgcn_rcpf(L3 + 1e-6f);
            o0.x = fminf(fmaxf(R.x  * r0r, 0.f), 1.f);
            o0.y = fminf(fmaxf(R.y  * r1r, 0.f), 1.f);
            o0.z = fminf(fmaxf(R.z  * r2r, 0.f), 1.f);
            o0.w = fminf(fmaxf(R.w  * r3r, 0.f), 1.f);
            o1.x = fminf(fmaxf(G.x  * r0r, 0.f), 1.f);
            o1.y = fminf(fmaxf(G.y  * r1r, 0.f), 1.f);
            o1.z = fminf(fmaxf(G.z  * r2r, 0.f), 1.f);
            o1.w = fminf(fmaxf(G.w  * r3r, 0.f), 1.f);
            o2.x = fminf(fmaxf(Bc.x * r0r, 0.f), 1.f);
            o2.y = fminf(fmaxf(Bc.y * r1r, 0.f), 1.f);
            o2.z = fminf(fmaxf(Bc.z * r2r, 0.f), 1.f);
            o2.w = fminf(fmaxf(Bc.w * r3r, 0.f), 1.f);
        }
        *(float4*)(qo)          = o0;
        *(float4*)(qo + HW)     = o1;
        *(float4*)(qo + 2 * HW) = o2;

        if (j < 3) { R = Rn; G = Gn; Bc = Bn; }
    }
}

extern "C" void kernel_launch(void* const* d_in, const int* in_sizes, int n_in,
                              void* d_out, int out_size, void* d_ws, size_t ws_size,
                              hipStream_t stream) {
    const float* x    = (const float*)d_in[0];
    const float* clar = (const float*)d_in[1];
    const float* tex  = (const float*)d_in[2];
    float* out = (float*)d_out;

    dim3 grid(8 * 16 * 16);  // 2048 blocks: 8 imgs x 16 strips x 16 bands; 6/CU resident
    dim3 block(256);
    hipLaunchKernelGGL(fused_tile, grid, block, 0, stream, x, clar, tex, out);
}

// Round 6
// 200.608 us; speedup vs baseline: 1.2693x; 1.2693x over previous
//
#include <hip/hip_runtime.h>
#include <hip/hip_fp16.h>
#include <cmath>

// Fixed problem shape: x = (8, 3, 1024, 1024) fp32.
#define HH   1024
#define WW   1024
#define HW   (HH * WW)

#define SW    64      // tile width  (output cols per block)
#define TH    64      // tile height (output rows per block)
#define T31R  94      // TH + 30
#define T7R   70      // TH + 6
#define NIT   6       // phase-1 iterations (6*16 = 96 >= 94 staged rows)
#define SPX   96      // stage row width in px (64 + 16 left + 16 right halo)
#define SOFF  16      // stage col s  <->  image col x0 - SOFF + s
#define UPR   24      // float4 units per stage row (24*4 = 96)

// ---- compile-time gaussian weights (matches np: exp(-d^2/(2 sigma^2)) / sum) ----
constexpr double cexp(double v) {
    double term = 1.0, sum = 1.0;
    for (int i = 1; i < 64; ++i) { term *= v / (double)i; sum += term; }
    return sum;
}
struct GW { float g31[31]; float g7[7]; };
constexpr GW make_gw() {
    GW r{};
    double t31[31]; double s31 = 0.0;
    for (int i = 0; i < 31; ++i) { double d = (double)(i - 15); t31[i] = cexp(-d * d / 128.0); s31 += t31[i]; }
    for (int i = 0; i < 31; ++i) r.g31[i] = (float)(t31[i] / s31);
    double t7[7]; double s7 = 0.0;
    for (int i = 0; i < 7; ++i) { double d = (double)(i - 3); t7[i] = cexp(-d * d / 4.5); s7 += t7[i]; }
    for (int i = 0; i < 7; ++i) r.g7[i] = (float)(t7[i] / s7);
    return r;
}
__constant__ GW GWC = make_gw();

// ---------------------------------------------------------------------------
// V6 vs V5 (dispatch 132µs REGRESSION, VGPR 40, WRITE_SIZE 98->262 MB):
// launch_bounds(256,6) forced the allocator below the kernel's natural
// ~64-VGPR need -> scratch spills (+166 MB write traffic) ate the occupancy
// gain. V6 keeps TH=64 (LDS 24064 B -> 6 blocks/CU possible) but reverts to
// launch_bounds(256,4): VGPR cap 128, compiler lands at its natural ~64,
// and 64 VGPR supports 8 waves/SIMD -> occupancy becomes LDS-limited at
// 6 blocks/CU = 24 waves/CU. TLP experiment, now without spills.
// Carried: branch-free masked staging, sched_barrier(0) prefetch pinning,
// barrier-free phase 1, single __syncthreads, 4-col direct-tap phase 2.
// ---------------------------------------------------------------------------
__global__ __launch_bounds__(256, 4)
void fused_tile(const float* __restrict__ x,
                const float* __restrict__ clar,
                const float* __restrict__ tex,
                float* __restrict__ out) {
    __shared__ __align__(16) __half t31s [T31R][SW];
    __shared__ __align__(16) __half t7s  [T7R][SW];
    __shared__ __align__(16) __half stage[4][4][SPX];   // per-wave private

    // XCD swizzle: the two vertically-adjacent bands of one (img,strip)
    // column land on the same XCD so the 30-row halo overlap reuses L2.
    const int id    = blockIdx.x;
    const int xcd   = id & 7;
    const int j8    = id >> 3;             // 0..255
    const int combo = j8 & 127;            // img*16 + strip
    const int sub   = j8 >> 7;             // 0..1
    const int band  = xcd * 2 + sub;       // 0..15
    const int img   = combo >> 4;
    const int strip = combo & 15;

    const int y0 = band * TH;
    const int x0 = strip * SW;
    const int t  = threadIdx.x;
    const int w    = t >> 6;               // wave 0..3
    const int lane = t & 63;

    const float* xb = x   + (size_t)img * 3 * HW;
    float*       ob = out + (size_t)img * 3 * HW;

    // ---- per-wave staging geometry: 4 rows x 24 units = 96 units over 64
    // lanes. unit0 = lane; unit1 = lane+64 (lanes >= 32 produce benign
    // duplicate writes of valid slots -> fully branch-free). ----
    const int r0s = lane / UPR;                 // 0..2
    const int c0s = lane - UPR * r0s;
    const int u1  = lane + 64;                  // 64..127
    const int r1r = u1 / UPR;                   // 2..5
    const int r1s = r1r > 3 ? 3 : r1r;          // clamp -> duplicate slots
    const int c1s = u1 - UPR * r1r;             // 0..23
    const int col0 = x0 - SOFF + 4 * c0s;
    const int col1 = x0 - SOFF + 4 * c1s;
    const int col0c = col0 < 0 ? 0 : (col0 > WW - 4 ? WW - 4 : col0);
    const int col1c = col1 < 0 ? 0 : (col1 > WW - 4 ? WW - 4 : col1);
    const float cm0 = ((unsigned)col0 < (unsigned)WW) ? 1.f : 0.f;
    const float cm1 = ((unsigned)col1 < (unsigned)WW) ? 1.f : 0.f;

    float4 R0, G0, B0, R1, G1, B1;
    float  mk0, mk1;

    // issue iteration `it`'s global loads into registers — UNCONDITIONAL
    // (clamped addresses), masks applied at consume time.
    auto issue = [&](int it) {
        const int gbase = it * 16;
        {
            const int tr = gbase + 4 * w + r0s;
            const int y  = y0 - 15 + tr;
            const int yc = y < 0 ? 0 : (y > HH - 1 ? HH - 1 : y);
            mk0 = (tr < T31R && (unsigned)y < (unsigned)HH) ? cm0 : 0.f;
            const float* xr = xb + (size_t)yc * WW + col0c;
            R0 = *(const float4*)(xr);
            G0 = *(const float4*)(xr + HW);
            B0 = *(const float4*)(xr + 2 * HW);
        }
        {
            const int tr = gbase + 4 * w + r1s;
            const int y  = y0 - 15 + tr;
            const int yc = y < 0 ? 0 : (y > HH - 1 ? HH - 1 : y);
            mk1 = (tr < T31R && (unsigned)y < (unsigned)HH) ? cm1 : 0.f;
            const float* xr = xb + (size_t)yc * WW + col1c;
            R1 = *(const float4*)(xr);
            G1 = *(const float4*)(xr + HW);
            B1 = *(const float4*)(xr + 2 * HW);
        }
    };

    issue(0);   // prologue
    __builtin_amdgcn_sched_barrier(0);

    // -------- phase 1: barrier-free; wave w stages and h-blurs its own
    // rows tr = 16*it + 4w + r. --------
    for (int it = 0; it < NIT; ++it) {
        // consume prefetched regs -> masked fp16 luma into stage
        {
            union { float2 f; __half2 h[2]; } W;
            W.h[0] = __floats2half2_rn(mk0 * fmaf(0.2126f, R0.x, fmaf(0.7152f, G0.x, 0.0722f * B0.x)),
                                       mk0 * fmaf(0.2126f, R0.y, fmaf(0.7152f, G0.y, 0.0722f * B0.y)));
            W.h[1] = __floats2half2_rn(mk0 * fmaf(0.2126f, R0.z, fmaf(0.7152f, G0.z, 0.0722f * B0.z)),
                                       mk0 * fmaf(0.2126f, R0.w, fmaf(0.7152f, G0.w, 0.0722f * B0.w)));
            *(float2*)&stage[w][r0s][4 * c0s] = W.f;   // 8-byte aligned
            union { float2 f; __half2 h[2]; } V;
            V.h[0] = __floats2half2_rn(mk1 * fmaf(0.2126f, R1.x, fmaf(0.7152f, G1.x, 0.0722f * B1.x)),
                                       mk1 * fmaf(0.2126f, R1.y, fmaf(0.7152f, G1.y, 0.0722f * B1.y)));
            V.h[1] = __floats2half2_rn(mk1 * fmaf(0.2126f, R1.z, fmaf(0.7152f, G1.z, 0.0722f * B1.z)),
                                       mk1 * fmaf(0.2126f, R1.w, fmaf(0.7152f, G1.w, 0.0722f * B1.w)));
            *(float2*)&stage[w][r1s][4 * c1s] = V.f;
        }

        // issue next iteration's loads and FENCE: the scheduler cannot sink
        // them past this point, so the h-blur below covers their latency.
        if (it + 1 < NIT) {
            issue(it + 1);
        }
        __builtin_amdgcn_sched_barrier(0);

        // h-blur: thread -> stage row (t>>4)&3 of its own wave, 4 px at 4*(t&15)
        {
            const int lr = (t >> 4) & 3;
            const int c  = t & 15;
            const int tr = it * 16 + (t >> 4);
            if (tr < T31R) {
                float win[36];
                #pragma unroll
                for (int q = 0; q < 9; ++q) {
                    union { float2 f; __half2 h[2]; } U;
                    // win[i] <-> stage col 4c+i <-> image col x0-16+4c+i
                    U.f = *(const float2*)&stage[w][lr][4 * c + 4 * q];  // 8B aligned
                    const float2 a = __half22float2(U.h[0]);
                    const float2 b = __half22float2(U.h[1]);
                    win[4 * q]     = a.x; win[4 * q + 1] = a.y;
                    win[4 * q + 2] = b.x; win[4 * q + 3] = b.y;
                }
                float o[4] = {0.f, 0.f, 0.f, 0.f};
                float p[4] = {0.f, 0.f, 0.f, 0.f};
                #pragma unroll
                for (int s = 0; s < 31; ++s) {
                    const float g = GWC.g31[s];
                    o[0] = fmaf(g, win[1 + s], o[0]);
                    o[1] = fmaf(g, win[2 + s], o[1]);
                    o[2] = fmaf(g, win[3 + s], o[2]);
                    o[3] = fmaf(g, win[4 + s], o[3]);
                }
                #pragma unroll
                for (int s = 0; s < 7; ++s) {
                    const float g = GWC.g7[s];
                    p[0] = fmaf(g, win[13 + s], p[0]);
                    p[1] = fmaf(g, win[14 + s], p[1]);
                    p[2] = fmaf(g, win[15 + s], p[2]);
                    p[3] = fmaf(g, win[16 + s], p[3]);
                }
                union { float2 f; __half2 h[2]; } W;
                W.h[0] = __floats2half2_rn(o[0], o[1]);
                W.h[1] = __floats2half2_rn(o[2], o[3]);
                *(float2*)&t31s[tr][4 * c] = W.f;
                if (tr >= 12 && tr < 12 + T7R) {
                    union { float2 f; __half2 h[2]; } V;
                    V.h[0] = __floats2half2_rn(p[0], p[1]);
                    V.h[1] = __floats2half2_rn(p[2], p[3]);
                    *(float2*)&t7s[tr - 12][4 * c] = V.f;
                }
            }
        }
        // NO __syncthreads here
    }

    __syncthreads();   // the ONLY barrier: t31s/t7s complete before phase 2

    // -------- phase 2: vertical blurs + combine, 4 cols/thread, direct
    // b64 tap reads from LDS (no register ring). --------
    const float ca = tanhf(clar[0]) * 0.5f;
    const float ta = tanhf(tex[0]) * 0.3f;

    const int rg = t >> 4;            // row group 0..15
    const int r0 = rg * 4;            // output rows r0..r0+3 (tile-rel)
    const int cc = 4 * (t & 15);      // col within tile, float4-aligned

    // prefetch x row j=0 (L2/L3-hot re-read)
    const float* p0 = xb + (size_t)(y0 + r0) * WW + x0 + cc;
    float4 R  = *(const float4*)(p0);
    float4 G  = *(const float4*)(p0 + HW);
    float4 Bc = *(const float4*)(p0 + 2 * HW);
    __builtin_amdgcn_sched_barrier(0);

    #pragma unroll
    for (int j = 0; j < 4; ++j) {
        // issue next row's x loads before the conv chain (latency cover)
        float4 Rn, Gn, Bn;
        if (j < 3) {
            const float* pn = xb + (size_t)(y0 + r0 + j + 1) * WW + x0 + cc;
            Rn = *(const float4*)(pn);
            Gn = *(const float4*)(pn + HW);
            Bn = *(const float4*)(pn + 2 * HW);
        }
        __builtin_amdgcn_sched_barrier(0);

        float4 a31 = make_float4(0.f, 0.f, 0.f, 0.f);
        #pragma unroll
        for (int q = 0; q < 31; ++q) {
            union { float2 f; __half2 h[2]; } U;
            U.f = *(const float2*)&t31s[r0 + j + q][cc];   // ds_read_b64
            const float2 a = __half22float2(U.h[0]);
            const float2 b = __half22float2(U.h[1]);
            const float g = GWC.g31[q];
            a31.x = fmaf(g, a.x, a31.x);
            a31.y = fmaf(g, a.y, a31.y);
            a31.z = fmaf(g, b.x, a31.z);
            a31.w = fmaf(g, b.y, a31.w);
        }
        float4 a7 = make_float4(0.f, 0.f, 0.f, 0.f);
        #pragma unroll
        for (int q = 0; q < 7; ++q) {
            union { float2 f; __half2 h[2]; } U;
            U.f = *(const float2*)&t7s[r0 + j + q][cc];    // ds_read_b64
            const float2 a = __half22float2(U.h[0]);
            const float2 b = __half22float2(U.h[1]);
            const float g = GWC.g7[q];
            a7.x = fmaf(g, a.x, a7.x);
            a7.y = fmaf(g, a.y, a7.y);
            a7.z = fmaf(g, b.x, a7.z);
            a7.w = fmaf(g, b.y, a7.w);
        }

        const int y = y0 + r0 + j;
        float* qo = ob + (size_t)y * WW + x0 + cc;

        float4 o0, o1, o2;
        {
            const float L0 = fmaf(0.2126f, R.x, fmaf(0.7152f, G.x, 0.0722f * Bc.x));
            const float L1 = fmaf(0.2126f, R.y, fmaf(0.7152f, G.y, 0.0722f * Bc.y));
            const float L2 = fmaf(0.2126f, R.z, fmaf(0.7152f, G.z, 0.0722f * Bc.z));
            const float L3 = fmaf(0.2126f, R.w, fmaf(0.7152f, G.w, 0.0722f * Bc.w));
            const float e0 = L0 + ca * (L0 - a31.x) + ta * (L0 - a7.x);
            const float e1 = L1 + ca * (L1 - a31.y) + ta * (L1 - a7.y);
            const float e2 = L2 + ca * (L2 - a31.z) + ta * (L2 - a7.z);
            const float e3 = L3 + ca * (L3 - a31.w) + ta * (L3 - a7.w);
            // v_rcp_f32 approx: rel err ~1ulp, far below the 3.9e-3 tolerance
            const float r0r = (e0 + 1e-6f) * __builtin_amdgcn_rcpf(L0 + 1e-6f);
            const float r1r = (e1 + 1e-6f) * __builtin_amdgcn_rcpf(L1 + 1e-6f);
            const float r2r = (e2 + 1e-6f) * __builtin_amdgcn_rcpf(L2 + 1e-6f);
            const float r3r = (e3 + 1e-6f) * __builtin_amdgcn_rcpf(L3 + 1e-6f);
            o0.x = fminf(fmaxf(R.x  * r0r, 0.f), 1.f);
            o0.y = fminf(fmaxf(R.y  * r1r, 0.f), 1.f);
            o0.z = fminf(fmaxf(R.z  * r2r, 0.f), 1.f);
            o0.w = fminf(fmaxf(R.w  * r3r, 0.f), 1.f);
            o1.x = fminf(fmaxf(G.x  * r0r, 0.f), 1.f);
            o1.y = fminf(fmaxf(G.y  * r1r, 0.f), 1.f);
            o1.z = fminf(fmaxf(G.z  * r2r, 0.f), 1.f);
            o1.w = fminf(fmaxf(G.w  * r3r, 0.f), 1.f);
            o2.x = fminf(fmaxf(Bc.x * r0r, 0.f), 1.f);
            o2.y = fminf(fmaxf(Bc.y * r1r, 0.f), 1.f);
            o2.z = fminf(fmaxf(Bc.z * r2r, 0.f), 1.f);
            o2.w = fminf(fmaxf(Bc.w * r3r, 0.f), 1.f);
        }
        *(float4*)(qo)          = o0;
        *(float4*)(qo + HW)     = o1;
        *(float4*)(qo + 2 * HW) = o2;

        if (j < 3) { R = Rn; G = Gn; Bc = Bn; }
    }
}

extern "C" void kernel_launch(void* const* d_in, const int* in_sizes, int n_in,
                              void* d_out, int out_size, void* d_ws, size_t ws_size,
                              hipStream_t stream) {
    const float* x    = (const float*)d_in[0];
    const float* clar = (const float*)d_in[1];
    const float* tex  = (const float*)d_in[2];
    float* out = (float*)d_out;

    dim3 grid(8 * 16 * 16);  // 2048 blocks: 8 imgs x 16 strips x 16 bands; 6/CU resident
    dim3 block(256);
    hipLaunchKernelGGL(fused_tile, grid, block, 0, stream, x, clar, tex, out);
}

// Round 7
// 198.476 us; speedup vs baseline: 1.2829x; 1.0107x over previous
//
#include <hip/hip_runtime.h>
#include <hip/hip_fp16.h>
#include <cmath>

// Fixed problem shape: x = (8, 3, 1024, 1024) fp32.
#define HH   1024
#define WW   1024
#define HW   (HH * WW)

#define SW    64      // tile width  (output cols per block)
#define TH    64      // tile height (output rows per block)
#define T31R  94      // TH + 30
#define T7R   70      // TH + 6
#define NIT   3       // phase-1 iterations (3*32 = 96 >= 94 staged rows)
#define SPX   96      // stage row width in px (64 + 16 left + 16 right halo)
#define SOFF  16      // stage col s  <->  image col x0 - SOFF + s
#define UPR   24      // float4 units per stage row (24*4 = 96)

// ---- compile-time gaussian weights (matches np: exp(-d^2/(2 sigma^2)) / sum) ----
constexpr double cexp(double v) {
    double term = 1.0, sum = 1.0;
    for (int i = 1; i < 64; ++i) { term *= v / (double)i; sum += term; }
    return sum;
}
struct GW { float g31[31]; float g7[7]; };
constexpr GW make_gw() {
    GW r{};
    double t31[31]; double s31 = 0.0;
    for (int i = 0; i < 31; ++i) { double d = (double)(i - 15); t31[i] = cexp(-d * d / 128.0); s31 += t31[i]; }
    for (int i = 0; i < 31; ++i) r.g31[i] = (float)(t31[i] / s31);
    double t7[7]; double s7 = 0.0;
    for (int i = 0; i < 7; ++i) { double d = (double)(i - 3); t7[i] = cexp(-d * d / 4.5); s7 += t7[i]; }
    for (int i = 0; i < 7; ++i) r.g7[i] = (float)(t7[i] / s7);
    return r;
}
__constant__ GW GWC = make_gw();

// ---------------------------------------------------------------------------
// V7 vs V6 (78µs flat, VALU 36%, HBM 35%, occ ~33%; VALU floor ~39µs of
// which ~half is v_cvt_f32_f16, HBM floor ~35µs; measured = sum -> both
// pipes under-utilized, overlap poor):
//  1. t31 tile -> fp32: phase-2's 31-tap loop reads ds_read_b128 with ZERO
//     conversions (was 124 cvt + 124 fma per row). VALU floor ~39 -> ~27µs.
//     b128 wave footprint = 4KB covering all 32 banks evenly -> no new
//     conflicts. t7 stays fp16 (28 cvt/row, cheap).
//  2. 512-thread blocks (8 waves): LDS = 24064 + 8960 + 6144 = 39168 B ->
//     4 blocks/CU = 32 waves/CU = HW MAX occupancy (was ~16). Grid 2048 =
//     exactly 2 rounds. Per-thread work halves (NIT=3, 2 rows/thr phase 2).
// Carried: branch-free masked staging, sched_barrier(0) prefetch pinning,
// barrier-free phase 1 (per-wave private stage rows), single __syncthreads.
// ---------------------------------------------------------------------------
__global__ __launch_bounds__(512, 4)
void fused_tile(const float* __restrict__ x,
                const float* __restrict__ clar,
                const float* __restrict__ tex,
                float* __restrict__ out) {
    __shared__ __align__(16) float  t31s [T31R][SW];      // 24064 B fp32
    __shared__ __align__(16) __half t7s  [T7R][SW];       //  8960 B fp16
    __shared__ __align__(16) __half stage[8][4][SPX];     //  6144 B per-wave

    // XCD swizzle: vertically-adjacent bands of one (img,strip) column land
    // on one XCD so the 30-row halo overlap reuses L2.
    const int id    = blockIdx.x;
    const int xcd   = id & 7;
    const int j8    = id >> 3;             // 0..255
    const int combo = j8 & 127;            // img*16 + strip
    const int sub   = j8 >> 7;             // 0..1
    const int band  = xcd * 2 + sub;       // 0..15
    const int img   = combo >> 4;
    const int strip = combo & 15;

    const int y0 = band * TH;
    const int x0 = strip * SW;
    const int t  = threadIdx.x;
    const int w    = t >> 6;               // wave 0..7
    const int lane = t & 63;

    const float* xb = x   + (size_t)img * 3 * HW;
    float*       ob = out + (size_t)img * 3 * HW;

    // ---- per-wave staging geometry: 4 rows x 24 units = 96 units over 64
    // lanes. unit0 = lane; unit1 = lane+64 (clamped duplicates for lanes
    // whose second unit exceeds 95 -> same slot, same data, branch-free) ----
    const int r0s = lane / UPR;                 // 0..2
    const int c0s = lane - UPR * r0s;
    const int u1  = lane + 64;                  // 64..127
    const int r1r = u1 / UPR;                   // 2..5
    const int r1s = r1r > 3 ? 3 : r1r;          // clamp -> duplicate slots
    const int c1s = u1 - UPR * r1r;             // 0..23
    const int col0 = x0 - SOFF + 4 * c0s;
    const int col1 = x0 - SOFF + 4 * c1s;
    const int col0c = col0 < 0 ? 0 : (col0 > WW - 4 ? WW - 4 : col0);
    const int col1c = col1 < 0 ? 0 : (col1 > WW - 4 ? WW - 4 : col1);
    const float cm0 = ((unsigned)col0 < (unsigned)WW) ? 1.f : 0.f;
    const float cm1 = ((unsigned)col1 < (unsigned)WW) ? 1.f : 0.f;

    float4 R0, G0, B0, R1, G1, B1;
    float  mk0, mk1;

    // issue iteration `it`'s global loads into registers — UNCONDITIONAL
    // (clamped addresses), masks applied at consume time.
    auto issue = [&](int it) {
        const int gbase = it * 32;
        {
            const int tr = gbase + 4 * w + r0s;
            const int y  = y0 - 15 + tr;
            const int yc = y < 0 ? 0 : (y > HH - 1 ? HH - 1 : y);
            mk0 = (tr < T31R && (unsigned)y < (unsigned)HH) ? cm0 : 0.f;
            const float* xr = xb + (size_t)yc * WW + col0c;
            R0 = *(const float4*)(xr);
            G0 = *(const float4*)(xr + HW);
            B0 = *(const float4*)(xr + 2 * HW);
        }
        {
            const int tr = gbase + 4 * w + r1s;
            const int y  = y0 - 15 + tr;
            const int yc = y < 0 ? 0 : (y > HH - 1 ? HH - 1 : y);
            mk1 = (tr < T31R && (unsigned)y < (unsigned)HH) ? cm1 : 0.f;
            const float* xr = xb + (size_t)yc * WW + col1c;
            R1 = *(const float4*)(xr);
            G1 = *(const float4*)(xr + HW);
            B1 = *(const float4*)(xr + 2 * HW);
        }
    };

    issue(0);   // prologue
    __builtin_amdgcn_sched_barrier(0);

    // -------- phase 1: barrier-free; wave w stages and h-blurs its own
    // rows tr = 32*it + 4w + r. --------
    for (int it = 0; it < NIT; ++it) {
        // consume prefetched regs -> masked fp16 luma into stage
        {
            union { float2 f; __half2 h[2]; } W;
            W.h[0] = __floats2half2_rn(mk0 * fmaf(0.2126f, R0.x, fmaf(0.7152f, G0.x, 0.0722f * B0.x)),
                                       mk0 * fmaf(0.2126f, R0.y, fmaf(0.7152f, G0.y, 0.0722f * B0.y)));
            W.h[1] = __floats2half2_rn(mk0 * fmaf(0.2126f, R0.z, fmaf(0.7152f, G0.z, 0.0722f * B0.z)),
                                       mk0 * fmaf(0.2126f, R0.w, fmaf(0.7152f, G0.w, 0.0722f * B0.w)));
            *(float2*)&stage[w][r0s][4 * c0s] = W.f;   // 8-byte aligned
            union { float2 f; __half2 h[2]; } V;
            V.h[0] = __floats2half2_rn(mk1 * fmaf(0.2126f, R1.x, fmaf(0.7152f, G1.x, 0.0722f * B1.x)),
                                       mk1 * fmaf(0.2126f, R1.y, fmaf(0.7152f, G1.y, 0.0722f * B1.y)));
            V.h[1] = __floats2half2_rn(mk1 * fmaf(0.2126f, R1.z, fmaf(0.7152f, G1.z, 0.0722f * B1.z)),
                                       mk1 * fmaf(0.2126f, R1.w, fmaf(0.7152f, G1.w, 0.0722f * B1.w)));
            *(float2*)&stage[w][r1s][4 * c1s] = V.f;
        }

        // issue next iteration's loads and FENCE: the scheduler cannot sink
        // them past this point, so the h-blur below covers their latency.
        if (it + 1 < NIT) {
            issue(it + 1);
        }
        __builtin_amdgcn_sched_barrier(0);

        // h-blur: thread -> stage row (t>>4)&3 of its own wave, 4 px at 4*(t&15)
        {
            const int lr = (t >> 4) & 3;
            const int c  = t & 15;
            const int tr = it * 32 + 4 * w + lr;
            if (tr < T31R) {
                float win[36];
                #pragma unroll
                for (int q = 0; q < 9; ++q) {
                    union { float2 f; __half2 h[2]; } U;
                    // win[i] <-> stage col 4c+i <-> image col x0-16+4c+i
                    U.f = *(const float2*)&stage[w][lr][4 * c + 4 * q];  // 8B aligned
                    const float2 a = __half22float2(U.h[0]);
                    const float2 b = __half22float2(U.h[1]);
                    win[4 * q]     = a.x; win[4 * q + 1] = a.y;
                    win[4 * q + 2] = b.x; win[4 * q + 3] = b.y;
                }
                float o[4] = {0.f, 0.f, 0.f, 0.f};
                float p[4] = {0.f, 0.f, 0.f, 0.f};
                #pragma unroll
                for (int s = 0; s < 31; ++s) {
                    const float g = GWC.g31[s];
                    o[0] = fmaf(g, win[1 + s], o[0]);
                    o[1] = fmaf(g, win[2 + s], o[1]);
                    o[2] = fmaf(g, win[3 + s], o[2]);
                    o[3] = fmaf(g, win[4 + s], o[3]);
                }
                #pragma unroll
                for (int s = 0; s < 7; ++s) {
                    const float g = GWC.g7[s];
                    p[0] = fmaf(g, win[13 + s], p[0]);
                    p[1] = fmaf(g, win[14 + s], p[1]);
                    p[2] = fmaf(g, win[15 + s], p[2]);
                    p[3] = fmaf(g, win[16 + s], p[3]);
                }
                // fp32 tile write: one b128
                *(float4*)&t31s[tr][4 * c] = make_float4(o[0], o[1], o[2], o[3]);
                if (tr >= 12 && tr < 12 + T7R) {
                    union { float2 f; __half2 h[2]; } V;
                    V.h[0] = __floats2half2_rn(p[0], p[1]);
                    V.h[1] = __floats2half2_rn(p[2], p[3]);
                    *(float2*)&t7s[tr - 12][4 * c] = V.f;
                }
            }
        }
        // NO __syncthreads here
    }

    __syncthreads();   // the ONLY barrier: t31s/t7s complete before phase 2

    // -------- phase 2: vertical blurs + combine, 4 cols x 2 rows/thread,
    // direct b128 fp32 taps (zero cvt) + b64 fp16 t7 taps. --------
    const float ca = tanhf(clar[0]) * 0.5f;
    const float ta = tanhf(tex[0]) * 0.3f;

    const int rg = t >> 4;            // row group 0..31
    const int r0 = rg * 2;            // output rows r0..r0+1 (tile-rel)
    const int cc = 4 * (t & 15);      // col within tile, float4-aligned

    // prefetch x row j=0 (L2/L3-hot re-read)
    const float* p0 = xb + (size_t)(y0 + r0) * WW + x0 + cc;
    float4 R  = *(const float4*)(p0);
    float4 G  = *(const float4*)(p0 + HW);
    float4 Bc = *(const float4*)(p0 + 2 * HW);
    __builtin_amdgcn_sched_barrier(0);

    #pragma unroll
    for (int j = 0; j < 2; ++j) {
        // issue next row's x loads before the conv chain (latency cover)
        float4 Rn, Gn, Bn;
        if (j < 1) {
            const float* pn = xb + (size_t)(y0 + r0 + j + 1) * WW + x0 + cc;
            Rn = *(const float4*)(pn);
            Gn = *(const float4*)(pn + HW);
            Bn = *(const float4*)(pn + 2 * HW);
        }
        __builtin_amdgcn_sched_barrier(0);

        float4 a31 = make_float4(0.f, 0.f, 0.f, 0.f);
        #pragma unroll
        for (int q = 0; q < 31; ++q) {
            const float4 wv = *(const float4*)&t31s[r0 + j + q][cc];  // b128, no cvt
            const float g = GWC.g31[q];
            a31.x = fmaf(g, wv.x, a31.x);
            a31.y = fmaf(g, wv.y, a31.y);
            a31.z = fmaf(g, wv.z, a31.z);
            a31.w = fmaf(g, wv.w, a31.w);
        }
        float4 a7 = make_float4(0.f, 0.f, 0.f, 0.f);
        #pragma unroll
        for (int q = 0; q < 7; ++q) {
            union { float2 f; __half2 h[2]; } U;
            U.f = *(const float2*)&t7s[r0 + j + q][cc];    // ds_read_b64
            const float2 a = __half22float2(U.h[0]);
            const float2 b = __half22float2(U.h[1]);
            const float g = GWC.g7[q];
            a7.x = fmaf(g, a.x, a7.x);
            a7.y = fmaf(g, a.y, a7.y);
            a7.z = fmaf(g, b.x, a7.z);
            a7.w = fmaf(g, b.y, a7.w);
        }

        const int y = y0 + r0 + j;
        float* qo = ob + (size_t)y * WW + x0 + cc;

        float4 o0, o1, o2;
        {
            const float L0 = fmaf(0.2126f, R.x, fmaf(0.7152f, G.x, 0.0722f * Bc.x));
            const float L1 = fmaf(0.2126f, R.y, fmaf(0.7152f, G.y, 0.0722f * Bc.y));
            const float L2 = fmaf(0.2126f, R.z, fmaf(0.7152f, G.z, 0.0722f * Bc.z));
            const float L3 = fmaf(0.2126f, R.w, fmaf(0.7152f, G.w, 0.0722f * Bc.w));
            const float e0 = L0 + ca * (L0 - a31.x) + ta * (L0 - a7.x);
            const float e1 = L1 + ca * (L1 - a31.y) + ta * (L1 - a7.y);
            const float e2 = L2 + ca * (L2 - a31.z) + ta * (L2 - a7.z);
            const float e3 = L3 + ca * (L3 - a31.w) + ta * (L3 - a7.w);
            // v_rcp_f32 approx: rel err ~1ulp, far below the 3.9e-3 tolerance
            const float r0r = (e0 + 1e-6f) * __builtin_amdgcn_rcpf(L0 + 1e-6f);
            const float r1r = (e1 + 1e-6f) * __builtin_amdgcn_rcpf(L1 + 1e-6f);
            const float r2r = (e2 + 1e-6f) * __builtin_amdgcn_rcpf(L2 + 1e-6f);
            const float r3r = (e3 + 1e-6f) * __builtin_amdgcn_rcpf(L3 + 1e-6f);
            o0.x = fminf(fmaxf(R.x  * r0r, 0.f), 1.f);
            o0.y = fminf(fmaxf(R.y  * r1r, 0.f), 1.f);
            o0.z = fminf(fmaxf(R.z  * r2r, 0.f), 1.f);
            o0.w = fminf(fmaxf(R.w  * r3r, 0.f), 1.f);
            o1.x = fminf(fmaxf(G.x  * r0r, 0.f), 1.f);
            o1.y = fminf(fmaxf(G.y  * r1r, 0.f), 1.f);
            o1.z = fminf(fmaxf(G.z  * r2r, 0.f), 1.f);
            o1.w = fminf(fmaxf(G.w  * r3r, 0.f), 1.f);
            o2.x = fminf(fmaxf(Bc.x * r0r, 0.f), 1.f);
            o2.y = fminf(fmaxf(Bc.y * r1r, 0.f), 1.f);
            o2.z = fminf(fmaxf(Bc.z * r2r, 0.f), 1.f);
            o2.w = fminf(fmaxf(Bc.w * r3r, 0.f), 1.f);
        }
        *(float4*)(qo)          = o0;
        *(float4*)(qo + HW)     = o1;
        *(float4*)(qo + 2 * HW) = o2;

        if (j < 1) { R = Rn; G = Gn; Bc = Bn; }
    }
}

extern "C" void kernel_launch(void* const* d_in, const int* in_sizes, int n_in,
                              void* d_out, int out_size, void* d_ws, size_t ws_size,
                              hipStream_t stream) {
    const float* x    = (const float*)d_in[0];
    const float* clar = (const float*)d_in[1];
    const float* tex  = (const float*)d_in[2];
    float* out = (float*)d_out;

    dim3 grid(8 * 16 * 16);  // 2048 blocks: 8 imgs x 16 strips x 16 bands; 4/CU x 2 rounds
    dim3 block(512);
    hipLaunchKernelGGL(fused_tile, grid, block, 0, stream, x, clar, tex, out);
}